// Round 1
// baseline (586.917 us; speedup 1.0000x reference)
//
#include <hip/hip_runtime.h>
#include <stdint.h>

#define NTOK 4096   // B*S tokens
#define DIM  1024   // model dim
#define NEXP 8      // experts
#define HID  4096   // expert hidden
#define CAP  1024   // capacity per expert = K*CAP_FACTOR*ceil(T/E)

typedef __bf16 bf16x8 __attribute__((ext_vector_type(8)));
typedef float  f32x4  __attribute__((ext_vector_type(4)));

__device__ __forceinline__ unsigned short f2bf(float f) {
  unsigned int u = __float_as_uint(f);
  return (unsigned short)((u + 0x7fffu + ((u >> 16) & 1u)) >> 16);  // RNE
}

__device__ __forceinline__ void load_lds16(const void* g, void* l) {
  __builtin_amdgcn_global_load_lds(
      (__attribute__((address_space(1))) void*)g,
      (__attribute__((address_space(3))) void*)l,
      16, 0, 0);
}

// ---------------- 1. gating: logits -> softmax -> top2 -> renorm ----------------
// one wave per token
__global__ void gating_kernel(const float* __restrict__ x, const float* __restrict__ wg,
                              int* __restrict__ tok_e, float* __restrict__ tok_g) {
  const int t = blockIdx.x;
  const int l = threadIdx.x;  // 0..63
  float acc[NEXP];
#pragma unroll
  for (int e = 0; e < NEXP; ++e) acc[e] = 0.f;

  const float4* x4  = (const float4*)(x + (size_t)t * DIM);
  const float4* wg4 = (const float4*)wg;  // wg[d][8] -> 2 float4 per row
#pragma unroll
  for (int i = 0; i < 4; ++i) {
    int dq = i * 64 + l;           // float4 index in row
    float4 xv = x4[dq];
    float xs[4] = {xv.x, xv.y, xv.z, xv.w};
#pragma unroll
    for (int c = 0; c < 4; ++c) {
      int d = dq * 4 + c;
      float4 wa = wg4[d * 2], wb = wg4[d * 2 + 1];
      acc[0] += xs[c] * wa.x; acc[1] += xs[c] * wa.y;
      acc[2] += xs[c] * wa.z; acc[3] += xs[c] * wa.w;
      acc[4] += xs[c] * wb.x; acc[5] += xs[c] * wb.y;
      acc[6] += xs[c] * wb.z; acc[7] += xs[c] * wb.w;
    }
  }
#pragma unroll
  for (int off = 32; off; off >>= 1)
#pragma unroll
    for (int e = 0; e < NEXP; ++e) acc[e] += __shfl_xor(acc[e], off);

  if (l == 0) {
    float m = acc[0];
#pragma unroll
    for (int e = 1; e < NEXP; ++e) m = fmaxf(m, acc[e]);
    float p[NEXP];
#pragma unroll
    for (int e = 0; e < NEXP; ++e) p[e] = __expf(acc[e] - m);
    // softmax denom cancels in top-2 renormalization
    int e0 = 0; float b0 = p[0];
#pragma unroll
    for (int e = 1; e < NEXP; ++e) if (p[e] > b0) { b0 = p[e]; e0 = e; }
    int e1 = -1; float b1v = -1.f;
#pragma unroll
    for (int e = 0; e < NEXP; ++e) if (e != e0 && p[e] > b1v) { b1v = p[e]; e1 = e; }
    float inv = 1.f / (b0 + b1v);
    tok_e[2 * t] = e0; tok_e[2 * t + 1] = e1;
    tok_g[2 * t] = b0 * inv; tok_g[2 * t + 1] = b1v * inv;
  }
}

// ---------------- 2. GShard slot-major cumsum: locations + slot map ----------------
// single wave; entry order g = k*T + t (slot-major, matches reference cumsum)
__global__ void scan_kernel(const int* __restrict__ tok_e, int* __restrict__ tok_loc,
                            int* __restrict__ slot_map) {
  const int l = threadIdx.x;  // 0..63
  const unsigned long long below = (1ull << l) - 1ull;
  int base[NEXP];
#pragma unroll
  for (int e = 0; e < NEXP; ++e) base[e] = 0;

  // prefetch chunk 0
  int nxt = tok_e[((0 * 64 + l) & (NTOK - 1)) * 2 + ((0 * 64 + l) >> 12)];
  for (int it = 0; it < 128; ++it) {
    int e = nxt;
    if (it + 1 < 128) {
      int g2 = (it + 1) * 64 + l;
      nxt = tok_e[(g2 & (NTOK - 1)) * 2 + (g2 >> 12)];
    }
    int loc = 0;
#pragma unroll
    for (int ex = 0; ex < NEXP; ++ex) {
      unsigned long long msk = __ballot(e == ex);
      int off = __popcll(msk & below);
      if (e == ex) loc = base[ex] + off;
      base[ex] += __popcll(msk);
    }
    int g = it * 64 + l;
    int k = g >> 12, t = g & (NTOK - 1);
    bool valid = loc < CAP;
    tok_loc[t * 2 + k] = valid ? loc : -1;
    if (valid) slot_map[e * CAP + loc] = t;
  }
  // mark unfilled slots (disjoint from scan writes -> no ordering hazard)
#pragma unroll
  for (int ex = 0; ex < NEXP; ++ex) {
    int c = base[ex] < CAP ? base[ex] : CAP;
    for (int i = c + l; i < CAP; i += 64) slot_map[ex * CAP + i] = -1;
  }
}

// ---------------- 3. dispatch: gather x rows -> disp[E,CAP,D] bf16 ----------------
__global__ void dispatch_kernel(const float* __restrict__ x, const int* __restrict__ slot_map,
                                unsigned short* __restrict__ disp) {
  const int s = blockIdx.x;      // slot 0..8191
  const int tid = threadIdx.x;   // 0..255, 4 elems each
  int t = slot_map[s];
  uint2 o;
  if (t >= 0) {
    float4 v = ((const float4*)(x + (size_t)t * DIM))[tid];
    o.x = (unsigned)f2bf(v.x) | ((unsigned)f2bf(v.y) << 16);
    o.y = (unsigned)f2bf(v.z) | ((unsigned)f2bf(v.w) << 16);
  } else {
    o.x = 0u; o.y = 0u;
  }
  ((uint2*)(disp + (size_t)s * DIM))[tid] = o;
}

// ---------------- 4. transpose fp32 [R,C] -> bf16 [C,R], per expert ----------------
__global__ void transpose_cvt(const float* __restrict__ in, unsigned short* __restrict__ out,
                              int R, int C) {
  __shared__ float tile[64][65];
  const int e = blockIdx.z;
  const float* inp = in + (size_t)e * R * C;
  unsigned short* outp = out + (size_t)e * R * C;
  const int c0 = blockIdx.x * 64, r0 = blockIdx.y * 64;
  const int tx = threadIdx.x, ty = threadIdx.y;  // (64,4)
#pragma unroll
  for (int i = 0; i < 16; ++i) {
    int r = ty + i * 4;
    tile[r][tx] = inp[(size_t)(r0 + r) * C + c0 + tx];
  }
  __syncthreads();
#pragma unroll
  for (int i = 0; i < 16; ++i) {
    int cl = ty + i * 4;
    outp[(size_t)(c0 + cl) * R + r0 + tx] = f2bf(tile[tx][cl]);
  }
}

// ---------------- 5/6. bf16 MFMA GEMM, m97 recipe ----------------
// A [M=1024][K] bf16 row-major, B [N][K] bf16 (K contiguous), C [M][N]
// 128x128 tile, BK=64, 256 threads (4 waves, 2x2), 4x4 16x16x32 mfma per wave
template <bool RELU, bool BF16OUT>
__global__ __launch_bounds__(256)
void gemm_kernel(const unsigned short* __restrict__ A, const unsigned short* __restrict__ B,
                 const float* __restrict__ bias, void* __restrict__ Cv, int N, int K) {
  constexpr int M = 1024;
  const int e = blockIdx.z;
  A += (size_t)e * M * K;
  B += (size_t)e * N * K;
  bias += (size_t)e * N;
  const int n0 = blockIdx.x * 128;
  const int m0 = blockIdx.y * 128;
  const int tid = threadIdx.x;
  const int wave = tid >> 6, lane = tid & 63;
  const int wm = wave >> 1, wn = wave & 1;

  __shared__ __align__(16) unsigned short As[128 * 64];
  __shared__ __align__(16) unsigned short Bs[128 * 64];

  // staging: each lane loads 16B; 8 lanes cover one 64-elem (128B) tile row
  const int srow = lane >> 3;          // row within wave's 8-row group
  const int scol = (lane & 7) * 8;     // bf16 offset within row
  const unsigned short* gA = A + (size_t)(m0 + wave * 8 + srow) * K + scol;
  const unsigned short* gB = B + (size_t)(n0 + wave * 8 + srow) * K + scol;
  unsigned short* lA = As + (wave * 8) * 64;  // wave-uniform LDS base
  unsigned short* lB = Bs + (wave * 8) * 64;

  f32x4 acc[4][4] = {};

  const int quad = lane >> 4;
  const int arow = (wm * 64 + (lane & 15)) * 64 + quad * 8;
  const int brow = (wn * 64 + (lane & 15)) * 64 + quad * 8;

  for (int k0 = 0; k0 < K; k0 += 64) {
    __syncthreads();
#pragma unroll
    for (int i = 0; i < 4; ++i) {
      load_lds16(gA + (size_t)i * 32 * K, lA + i * 32 * 64);
      load_lds16(gB + (size_t)i * 32 * K, lB + i * 32 * 64);
    }
    gA += 64; gB += 64;
    __syncthreads();
#pragma unroll
    for (int kk = 0; kk < 64; kk += 32) {
      bf16x8 af[4], bfr[4];
#pragma unroll
      for (int i = 0; i < 4; ++i)
        af[i] = *reinterpret_cast<const bf16x8*>(&As[arow + i * 16 * 64 + kk]);
#pragma unroll
      for (int j = 0; j < 4; ++j)
        bfr[j] = *reinterpret_cast<const bf16x8*>(&Bs[brow + j * 16 * 64 + kk]);
#pragma unroll
      for (int i = 0; i < 4; ++i)
#pragma unroll
        for (int j = 0; j < 4; ++j)
          acc[i][j] = __builtin_amdgcn_mfma_f32_16x16x32_bf16(af[i], bfr[j], acc[i][j], 0, 0, 0);
    }
  }

  // epilogue: C/D layout col=lane&15, row=quad*4+reg
  const int crow = m0 + wm * 64 + quad * 4;
  const int ccol = n0 + wn * 64 + (lane & 15);
  unsigned short* Cb = (unsigned short*)Cv + (size_t)e * M * N;
  float* Cf = (float*)Cv + (size_t)e * M * N;
#pragma unroll
  for (int j = 0; j < 4; ++j) {
    float bj = bias[ccol + j * 16];
#pragma unroll
    for (int i = 0; i < 4; ++i) {
#pragma unroll
      for (int r = 0; r < 4; ++r) {
        float v = acc[i][j][r] + bj;
        if (RELU) v = fmaxf(v, 0.f);
        size_t off = (size_t)(crow + i * 16 + r) * N + (ccol + j * 16);
        if (BF16OUT) Cb[off] = f2bf(v);
        else         Cf[off] = v;
      }
    }
  }
}

// ---------------- 7. combine: gate-weighted gather of expert outputs ----------------
__global__ void combine_kernel(const float* __restrict__ outb, const int* __restrict__ tok_e,
                               const int* __restrict__ tok_loc, const float* __restrict__ tok_g,
                               float* __restrict__ y) {
  const int t = blockIdx.x;
  const int tid = threadIdx.x;  // 0..255, float4 each
  int e0 = tok_e[2 * t], e1 = tok_e[2 * t + 1];
  int l0 = tok_loc[2 * t], l1 = tok_loc[2 * t + 1];
  float g0 = tok_g[2 * t], g1 = tok_g[2 * t + 1];
  float ax = 0.f, ay = 0.f, az = 0.f, aw = 0.f;
  if (l0 >= 0) {
    float4 v = ((const float4*)(outb + ((size_t)e0 * CAP + l0) * DIM))[tid];
    ax += g0 * v.x; ay += g0 * v.y; az += g0 * v.z; aw += g0 * v.w;
  }
  if (l1 >= 0) {
    float4 v = ((const float4*)(outb + ((size_t)e1 * CAP + l1) * DIM))[tid];
    ax += g1 * v.x; ay += g1 * v.y; az += g1 * v.z; aw += g1 * v.w;
  }
  float4 o; o.x = ax; o.y = ay; o.z = az; o.w = aw;
  ((float4*)(y + (size_t)t * DIM))[tid] = o;
}

extern "C" void kernel_launch(void* const* d_in, const int* in_sizes, int n_in,
                              void* d_out, int out_size, void* d_ws, size_t ws_size,
                              hipStream_t stream) {
  const float* x  = (const float*)d_in[0];
  const float* wg = (const float*)d_in[1];
  const float* w1 = (const float*)d_in[2];
  const float* b1 = (const float*)d_in[3];
  const float* w2 = (const float*)d_in[4];
  const float* b2 = (const float*)d_in[5];
  float* y = (float*)d_out;

  char* ws = (char*)d_ws;
  int*   tok_e    = (int*)(ws);
  int*   tok_loc  = (int*)(ws + 32768);
  float* tok_g    = (float*)(ws + 65536);
  int*   slot_map = (int*)(ws + 98304);
  unsigned short* disp = (unsigned short*)(ws + 131072);                          // 16 MiB
  unsigned short* wbuf = (unsigned short*)(ws + 131072 + (16ull << 20));          // 64 MiB
  unsigned short* h    = (unsigned short*)(ws + 131072 + (80ull << 20));          // 64 MiB
  float*          outb = (float*)(ws + 131072 + (144ull << 20));                  // 32 MiB
  // total: 176 MiB + 128 KiB

  gating_kernel<<<NTOK, 64, 0, stream>>>(x, wg, tok_e, tok_g);
  scan_kernel<<<1, 64, 0, stream>>>(tok_e, tok_loc, slot_map);
  dispatch_kernel<<<NEXP * CAP, 256, 0, stream>>>(x, slot_map, disp);
  // w1 [E][D][H] -> wbuf [E][H][D] bf16
  transpose_cvt<<<dim3(HID / 64, DIM / 64, NEXP), dim3(64, 4), 0, stream>>>(w1, wbuf, DIM, HID);
  // h = relu(disp @ w1 + b1): M=1024, N=HID, K=DIM
  gemm_kernel<true, true><<<dim3(HID / 128, CAP / 128, NEXP), 256, 0, stream>>>(
      disp, wbuf, b1, h, HID, DIM);
  // w2 [E][H][D] -> wbuf [E][D][H] bf16
  transpose_cvt<<<dim3(DIM / 64, HID / 64, NEXP), dim3(64, 4), 0, stream>>>(w2, wbuf, HID, DIM);
  // out = h @ w2 + b2: M=1024, N=DIM, K=HID
  gemm_kernel<false, false><<<dim3(DIM / 128, CAP / 128, NEXP), 256, 0, stream>>>(
      h, wbuf, b2, outb, DIM, HID);
  combine_kernel<<<NTOK, 256, 0, stream>>>(outb, tok_e, tok_loc, tok_g, y);
}

// Round 2
// 580.329 us; speedup vs baseline: 1.0114x; 1.0114x over previous
//
#include <hip/hip_runtime.h>
#include <stdint.h>

#define NTOK 4096   // B*S tokens
#define DIM  1024   // model dim
#define NEXP 8      // experts
#define HID  4096   // expert hidden
#define CAP  1024   // capacity per expert

typedef __bf16 bf16x8 __attribute__((ext_vector_type(8)));
typedef float  f32x4  __attribute__((ext_vector_type(4)));

__device__ __forceinline__ unsigned short f2bf(float f) {
  unsigned int u = __float_as_uint(f);
  return (unsigned short)((u + 0x7fffu + ((u >> 16) & 1u)) >> 16);  // RNE
}

__device__ __forceinline__ float bf2f(unsigned int bits16) {
  return __uint_as_float(bits16 << 16);
}

__device__ __forceinline__ void load_lds16(const void* g, void* l) {
  __builtin_amdgcn_global_load_lds(
      (__attribute__((address_space(1))) void*)g,
      (__attribute__((address_space(3))) void*)l,
      16, 0, 0);
}

// ---------------- 1. gating ----------------
__global__ void gating_kernel(const float* __restrict__ x, const float* __restrict__ wg,
                              int* __restrict__ tok_e, float* __restrict__ tok_g) {
  const int t = blockIdx.x;
  const int l = threadIdx.x;
  float acc[NEXP];
#pragma unroll
  for (int e = 0; e < NEXP; ++e) acc[e] = 0.f;

  const float4* x4  = (const float4*)(x + (size_t)t * DIM);
  const float4* wg4 = (const float4*)wg;
#pragma unroll
  for (int i = 0; i < 4; ++i) {
    int dq = i * 64 + l;
    float4 xv = x4[dq];
    float xs[4] = {xv.x, xv.y, xv.z, xv.w};
#pragma unroll
    for (int c = 0; c < 4; ++c) {
      int d = dq * 4 + c;
      float4 wa = wg4[d * 2], wb = wg4[d * 2 + 1];
      acc[0] += xs[c] * wa.x; acc[1] += xs[c] * wa.y;
      acc[2] += xs[c] * wa.z; acc[3] += xs[c] * wa.w;
      acc[4] += xs[c] * wb.x; acc[5] += xs[c] * wb.y;
      acc[6] += xs[c] * wb.z; acc[7] += xs[c] * wb.w;
    }
  }
#pragma unroll
  for (int off = 32; off; off >>= 1)
#pragma unroll
    for (int e = 0; e < NEXP; ++e) acc[e] += __shfl_xor(acc[e], off);

  if (l == 0) {
    float m = acc[0];
#pragma unroll
    for (int e = 1; e < NEXP; ++e) m = fmaxf(m, acc[e]);
    float p[NEXP];
#pragma unroll
    for (int e = 0; e < NEXP; ++e) p[e] = __expf(acc[e] - m);
    int e0 = 0; float b0 = p[0];
#pragma unroll
    for (int e = 1; e < NEXP; ++e) if (p[e] > b0) { b0 = p[e]; e0 = e; }
    int e1 = -1; float b1v = -1.f;
#pragma unroll
    for (int e = 0; e < NEXP; ++e) if (e != e0 && p[e] > b1v) { b1v = p[e]; e1 = e; }
    float inv = 1.f / (b0 + b1v);
    tok_e[2 * t] = e0; tok_e[2 * t + 1] = e1;
    tok_g[2 * t] = b0 * inv; tok_g[2 * t + 1] = b1v * inv;
  }
}

// ---------------- 2. GShard slot-major cumsum ----------------
__global__ void scan_kernel(const int* __restrict__ tok_e, int* __restrict__ tok_loc,
                            int* __restrict__ slot_map) {
  const int l = threadIdx.x;
  const unsigned long long below = (1ull << l) - 1ull;
  int base[NEXP];
#pragma unroll
  for (int e = 0; e < NEXP; ++e) base[e] = 0;

  int nxt = tok_e[((0 * 64 + l) & (NTOK - 1)) * 2 + ((0 * 64 + l) >> 12)];
  for (int it = 0; it < 128; ++it) {
    int e = nxt;
    if (it + 1 < 128) {
      int g2 = (it + 1) * 64 + l;
      nxt = tok_e[(g2 & (NTOK - 1)) * 2 + (g2 >> 12)];
    }
    int loc = 0;
#pragma unroll
    for (int ex = 0; ex < NEXP; ++ex) {
      unsigned long long msk = __ballot(e == ex);
      int off = __popcll(msk & below);
      if (e == ex) loc = base[ex] + off;
      base[ex] += __popcll(msk);
    }
    int g = it * 64 + l;
    int k = g >> 12, t = g & (NTOK - 1);
    bool valid = loc < CAP;
    tok_loc[t * 2 + k] = valid ? loc : -1;
    if (valid) slot_map[e * CAP + loc] = t;
  }
#pragma unroll
  for (int ex = 0; ex < NEXP; ++ex) {
    int c = base[ex] < CAP ? base[ex] : CAP;
    for (int i = c + l; i < CAP; i += 64) slot_map[ex * CAP + i] = -1;
  }
}

// ---------------- 3. dispatch: gather x rows -> disp[E,CAP,D] bf16 ----------------
__global__ void dispatch_kernel(const float* __restrict__ x, const int* __restrict__ slot_map,
                                unsigned short* __restrict__ disp) {
  const int s = blockIdx.x;
  const int tid = threadIdx.x;
  int t = slot_map[s];
  uint2 o;
  if (t >= 0) {
    float4 v = ((const float4*)(x + (size_t)t * DIM))[tid];
    o.x = (unsigned)f2bf(v.x) | ((unsigned)f2bf(v.y) << 16);
    o.y = (unsigned)f2bf(v.z) | ((unsigned)f2bf(v.w) << 16);
  } else {
    o.x = 0u; o.y = 0u;
  }
  ((uint2*)(disp + (size_t)s * DIM))[tid] = o;
}

// ---------------- 4. transpose fp32 [R,C] -> bf16 [C,R] per expert ----------------
// block 256 threads, 64x64 tile; float4 loads, 8B bf16x4 stores
__global__ void transpose_cvt(const float* __restrict__ in, unsigned short* __restrict__ out,
                              int R, int C) {
  __shared__ float tile[64][65];
  const int e = blockIdx.z;
  const float* inp = in + (size_t)e * R * C;
  unsigned short* outp = out + (size_t)e * R * C;
  const int c0 = blockIdx.x * 64, r0 = blockIdx.y * 64;
  const int t = threadIdx.x;
#pragma unroll
  for (int i = 0; i < 4; ++i) {
    int idx = i * 256 + t;          // float4 index in 64x64 tile
    int r = idx >> 4;
    int c4 = (idx & 15) * 4;
    float4 v = *(const float4*)(inp + (size_t)(r0 + r) * C + c0 + c4);
    tile[r][c4 + 0] = v.x; tile[r][c4 + 1] = v.y;
    tile[r][c4 + 2] = v.z; tile[r][c4 + 3] = v.w;
  }
  __syncthreads();
#pragma unroll
  for (int i = 0; i < 4; ++i) {
    int idx = i * 256 + t;          // (col, 4-row group)
    int c = idx >> 4;
    int r4 = (idx & 15) * 4;
    float a = tile[r4 + 0][c], b = tile[r4 + 1][c];
    float d0 = tile[r4 + 2][c], d1 = tile[r4 + 3][c];
    uint2 o;
    o.x = (unsigned)f2bf(a) | ((unsigned)f2bf(b) << 16);
    o.y = (unsigned)f2bf(d0) | ((unsigned)f2bf(d1) << 16);
    *(uint2*)(outp + (size_t)(c0 + c) * R + r0 + r4) = o;
  }
}

// ---------------- 5/6. bf16 MFMA GEMM: dbuf LDS + locality swizzle ----------------
// A [M=1024][K] bf16, B [N][K] bf16, C [M][N] bf16. 128x128 tile, BK=64.
// Flat grid, expert-major; within expert: patches of (MB m-tiles x 4 n-tiles)
// so the expert's whole A panel stays LLC-resident and B streams once.
template <bool RELU, int MB, int NB>
__global__ __launch_bounds__(256)
void gemm_kernel(const unsigned short* __restrict__ A, const unsigned short* __restrict__ B,
                 const float* __restrict__ bias, unsigned short* __restrict__ C,
                 int N, int K) {
  constexpr int M = 1024;
  const int bid = blockIdx.x;
  const int e = bid / (MB * NB);
  const int r = bid - e * (MB * NB);
  const int patch = r / (MB * 4);
  const int q = r - patch * (MB * 4);
  const int mtile = q >> 2;
  const int ntile = patch * 4 + (q & 3);

  A += (size_t)e * M * K;
  B += (size_t)e * N * K;
  bias += (size_t)e * N;
  C += (size_t)e * M * N;
  const int m0 = mtile * 128;
  const int n0 = ntile * 128;
  const int tid = threadIdx.x;
  const int wave = tid >> 6, lane = tid & 63;
  const int wm = wave >> 1, wn = wave & 1;

  __shared__ __align__(16) unsigned short As[2][128 * 64];
  __shared__ __align__(16) unsigned short Bs[2][128 * 64];

  const int srow = lane >> 3;
  const int scol = (lane & 7) * 8;
  const unsigned short* gA = A + (size_t)(m0 + wave * 8 + srow) * K + scol;
  const unsigned short* gB = B + (size_t)(n0 + wave * 8 + srow) * K + scol;
  const int lbase = (wave * 8) * 64;  // wave-uniform LDS base (elements)

  f32x4 acc[4][4] = {};

  const int quad = lane >> 4;
  const int arow = (wm * 64 + (lane & 15)) * 64 + quad * 8;
  const int brow = (wn * 64 + (lane & 15)) * 64 + quad * 8;

  // prologue: fill buffer 0
#pragma unroll
  for (int i = 0; i < 4; ++i) {
    load_lds16(gA + (size_t)i * 32 * K, &As[0][lbase + i * 32 * 64]);
    load_lds16(gB + (size_t)i * 32 * K, &Bs[0][lbase + i * 32 * 64]);
  }
  gA += 64; gB += 64;

  const int nIter = K >> 6;
  for (int it = 0; it < nIter; ++it) {
    const int cur = it & 1;
    __syncthreads();  // drains loads into buf[cur]; fences prev compute
    if (it + 1 < nIter) {
#pragma unroll
      for (int i = 0; i < 4; ++i) {
        load_lds16(gA + (size_t)i * 32 * K, &As[cur ^ 1][lbase + i * 32 * 64]);
        load_lds16(gB + (size_t)i * 32 * K, &Bs[cur ^ 1][lbase + i * 32 * 64]);
      }
      gA += 64; gB += 64;
    }
#pragma unroll
    for (int kk = 0; kk < 64; kk += 32) {
      bf16x8 af[4], bfr[4];
#pragma unroll
      for (int i = 0; i < 4; ++i)
        af[i] = *reinterpret_cast<const bf16x8*>(&As[cur][arow + i * 16 * 64 + kk]);
#pragma unroll
      for (int j = 0; j < 4; ++j)
        bfr[j] = *reinterpret_cast<const bf16x8*>(&Bs[cur][brow + j * 16 * 64 + kk]);
#pragma unroll
      for (int i = 0; i < 4; ++i)
#pragma unroll
        for (int j = 0; j < 4; ++j)
          acc[i][j] = __builtin_amdgcn_mfma_f32_16x16x32_bf16(af[i], bfr[j], acc[i][j], 0, 0, 0);
    }
  }

  // epilogue: C/D layout col=lane&15, row=quad*4+reg
  const int crow = m0 + wm * 64 + quad * 4;
  const int ccol = n0 + wn * 64 + (lane & 15);
#pragma unroll
  for (int j = 0; j < 4; ++j) {
    float bj = bias[ccol + j * 16];
#pragma unroll
    for (int i = 0; i < 4; ++i) {
#pragma unroll
      for (int rr = 0; rr < 4; ++rr) {
        float v = acc[i][j][rr] + bj;
        if (RELU) v = fmaxf(v, 0.f);
        C[(size_t)(crow + i * 16 + rr) * N + (ccol + j * 16)] = f2bf(v);
      }
    }
  }
}

// ---------------- 7. combine: gate-weighted gather (bf16 expert out) ----------------
__global__ void combine_kernel(const unsigned short* __restrict__ outb,
                               const int* __restrict__ tok_e, const int* __restrict__ tok_loc,
                               const float* __restrict__ tok_g, float* __restrict__ y) {
  const int t = blockIdx.x;
  const int tid = threadIdx.x;  // 0..255, 4 bf16 each
  int e0 = tok_e[2 * t], e1 = tok_e[2 * t + 1];
  int l0 = tok_loc[2 * t], l1 = tok_loc[2 * t + 1];
  float g0 = tok_g[2 * t], g1 = tok_g[2 * t + 1];
  float ax = 0.f, ay = 0.f, az = 0.f, aw = 0.f;
  if (l0 >= 0) {
    uint2 u = ((const uint2*)(outb + ((size_t)e0 * CAP + l0) * DIM))[tid];
    ax += g0 * bf2f(u.x & 0xffffu); ay += g0 * __uint_as_float(u.x & 0xffff0000u);
    az += g0 * bf2f(u.y & 0xffffu); aw += g0 * __uint_as_float(u.y & 0xffff0000u);
  }
  if (l1 >= 0) {
    uint2 u = ((const uint2*)(outb + ((size_t)e1 * CAP + l1) * DIM))[tid];
    ax += g1 * bf2f(u.x & 0xffffu); ay += g1 * __uint_as_float(u.x & 0xffff0000u);
    az += g1 * bf2f(u.y & 0xffffu); aw += g1 * __uint_as_float(u.y & 0xffff0000u);
  }
  float4 o; o.x = ax; o.y = ay; o.z = az; o.w = aw;
  ((float4*)(y + (size_t)t * DIM))[tid] = o;
}

extern "C" void kernel_launch(void* const* d_in, const int* in_sizes, int n_in,
                              void* d_out, int out_size, void* d_ws, size_t ws_size,
                              hipStream_t stream) {
  const float* x  = (const float*)d_in[0];
  const float* wg = (const float*)d_in[1];
  const float* w1 = (const float*)d_in[2];
  const float* b1 = (const float*)d_in[3];
  const float* w2 = (const float*)d_in[4];
  const float* b2 = (const float*)d_in[5];
  float* y = (float*)d_out;

  char* ws = (char*)d_ws;
  int*   tok_e    = (int*)(ws);
  int*   tok_loc  = (int*)(ws + 32768);
  float* tok_g    = (float*)(ws + 65536);
  int*   slot_map = (int*)(ws + 98304);
  unsigned short* disp = (unsigned short*)(ws + 131072);                      // 16 MiB
  unsigned short* wbuf = (unsigned short*)(ws + 131072 + (16ull << 20));      // 64 MiB
  unsigned short* h    = (unsigned short*)(ws + 131072 + (80ull << 20));      // 64 MiB
  unsigned short* outb = (unsigned short*)(ws + 131072 + (144ull << 20));     // 16 MiB
  // total: 160 MiB + 128 KiB

  gating_kernel<<<NTOK, 64, 0, stream>>>(x, wg, tok_e, tok_g);
  scan_kernel<<<1, 64, 0, stream>>>(tok_e, tok_loc, slot_map);
  dispatch_kernel<<<NEXP * CAP, 256, 0, stream>>>(x, slot_map, disp);
  // w1 [E][D][H] -> wbuf [E][H][D] bf16
  transpose_cvt<<<dim3(HID / 64, DIM / 64, NEXP), 256, 0, stream>>>(w1, wbuf, DIM, HID);
  // h = relu(disp @ w1 + b1): M=1024, N=HID=4096, K=DIM=1024; MB=8, NB=32
  gemm_kernel<true, 8, 32><<<NEXP * 8 * 32, 256, 0, stream>>>(disp, wbuf, b1, h, HID, DIM);
  // w2 [E][H][D] -> wbuf [E][D][H] bf16
  transpose_cvt<<<dim3(DIM / 64, HID / 64, NEXP), 256, 0, stream>>>(w2, wbuf, HID, DIM);
  // out = h @ w2 + b2: M=1024, N=DIM=1024, K=HID=4096; MB=8, NB=8
  gemm_kernel<false, 8, 8><<<NEXP * 8 * 8, 256, 0, stream>>>(h, wbuf, b2, outb, DIM, HID);
  combine_kernel<<<NTOK, 256, 0, stream>>>(outb, tok_e, tok_loc, tok_g, y);
}

// Round 3
// 540.469 us; speedup vs baseline: 1.0859x; 1.0738x over previous
//
#include <hip/hip_runtime.h>
#include <stdint.h>

#define NTOK 4096   // B*S tokens
#define DIM  1024   // model dim
#define NEXP 8      // experts
#define HID  4096   // expert hidden
#define CAP  1024   // capacity per expert

typedef __bf16 bf16x8 __attribute__((ext_vector_type(8)));
typedef float  f32x4  __attribute__((ext_vector_type(4)));

__device__ __forceinline__ unsigned short f2bf(float f) {
  unsigned int u = __float_as_uint(f);
  return (unsigned short)((u + 0x7fffu + ((u >> 16) & 1u)) >> 16);  // RNE
}

__device__ __forceinline__ float bf2f(unsigned int bits16) {
  return __uint_as_float(bits16 << 16);
}

__device__ __forceinline__ void load_lds16(const void* g, void* l) {
  __builtin_amdgcn_global_load_lds(
      (__attribute__((address_space(1))) void*)g,
      (__attribute__((address_space(3))) void*)l,
      16, 0, 0);
}

// ---------------- 1. gating ----------------
__global__ void gating_kernel(const float* __restrict__ x, const float* __restrict__ wg,
                              int* __restrict__ tok_e, float* __restrict__ tok_g) {
  const int t = blockIdx.x;
  const int l = threadIdx.x;
  float acc[NEXP];
#pragma unroll
  for (int e = 0; e < NEXP; ++e) acc[e] = 0.f;

  const float4* x4  = (const float4*)(x + (size_t)t * DIM);
  const float4* wg4 = (const float4*)wg;
#pragma unroll
  for (int i = 0; i < 4; ++i) {
    int dq = i * 64 + l;
    float4 xv = x4[dq];
    float xs[4] = {xv.x, xv.y, xv.z, xv.w};
#pragma unroll
    for (int c = 0; c < 4; ++c) {
      int d = dq * 4 + c;
      float4 wa = wg4[d * 2], wb = wg4[d * 2 + 1];
      acc[0] += xs[c] * wa.x; acc[1] += xs[c] * wa.y;
      acc[2] += xs[c] * wa.z; acc[3] += xs[c] * wa.w;
      acc[4] += xs[c] * wb.x; acc[5] += xs[c] * wb.y;
      acc[6] += xs[c] * wb.z; acc[7] += xs[c] * wb.w;
    }
  }
#pragma unroll
  for (int off = 32; off; off >>= 1)
#pragma unroll
    for (int e = 0; e < NEXP; ++e) acc[e] += __shfl_xor(acc[e], off);

  if (l == 0) {
    float m = acc[0];
#pragma unroll
    for (int e = 1; e < NEXP; ++e) m = fmaxf(m, acc[e]);
    float p[NEXP];
#pragma unroll
    for (int e = 0; e < NEXP; ++e) p[e] = __expf(acc[e] - m);
    int e0 = 0; float b0 = p[0];
#pragma unroll
    for (int e = 1; e < NEXP; ++e) if (p[e] > b0) { b0 = p[e]; e0 = e; }
    int e1 = -1; float b1v = -1.f;
#pragma unroll
    for (int e = 0; e < NEXP; ++e) if (e != e0 && p[e] > b1v) { b1v = p[e]; e1 = e; }
    float inv = 1.f / (b0 + b1v);
    tok_e[2 * t] = e0; tok_e[2 * t + 1] = e1;
    tok_g[2 * t] = b0 * inv; tok_g[2 * t + 1] = b1v * inv;
  }
}

// ---------------- 2. GShard slot-major cumsum ----------------
__global__ void scan_kernel(const int* __restrict__ tok_e, int* __restrict__ tok_loc,
                            int* __restrict__ slot_map) {
  const int l = threadIdx.x;
  const unsigned long long below = (1ull << l) - 1ull;
  int base[NEXP];
#pragma unroll
  for (int e = 0; e < NEXP; ++e) base[e] = 0;

  int nxt = tok_e[((0 * 64 + l) & (NTOK - 1)) * 2 + ((0 * 64 + l) >> 12)];
  for (int it = 0; it < 128; ++it) {
    int e = nxt;
    if (it + 1 < 128) {
      int g2 = (it + 1) * 64 + l;
      nxt = tok_e[(g2 & (NTOK - 1)) * 2 + (g2 >> 12)];
    }
    int loc = 0;
#pragma unroll
    for (int ex = 0; ex < NEXP; ++ex) {
      unsigned long long msk = __ballot(e == ex);
      int off = __popcll(msk & below);
      if (e == ex) loc = base[ex] + off;
      base[ex] += __popcll(msk);
    }
    int g = it * 64 + l;
    int k = g >> 12, t = g & (NTOK - 1);
    bool valid = loc < CAP;
    tok_loc[t * 2 + k] = valid ? loc : -1;
    if (valid) slot_map[e * CAP + loc] = t;
  }
#pragma unroll
  for (int ex = 0; ex < NEXP; ++ex) {
    int c = base[ex] < CAP ? base[ex] : CAP;
    for (int i = c + l; i < CAP; i += 64) slot_map[ex * CAP + i] = -1;
  }
}

// ---------------- 3. dispatch: gather x rows -> disp[E,CAP,D] bf16 ----------------
__global__ void dispatch_kernel(const float* __restrict__ x, const int* __restrict__ slot_map,
                                unsigned short* __restrict__ disp) {
  const int s = blockIdx.x;
  const int tid = threadIdx.x;
  int t = slot_map[s];
  uint2 o;
  if (t >= 0) {
    float4 v = ((const float4*)(x + (size_t)t * DIM))[tid];
    o.x = (unsigned)f2bf(v.x) | ((unsigned)f2bf(v.y) << 16);
    o.y = (unsigned)f2bf(v.z) | ((unsigned)f2bf(v.w) << 16);
  } else {
    o.x = 0u; o.y = 0u;
  }
  ((uint2*)(disp + (size_t)s * DIM))[tid] = o;
}

// ---------------- 4. transpose fp32 [R,C] -> bf16 [C,R] per expert ----------------
// 256 threads, 64x64 tile; float4 loads, 16B bf16x8 stores
__global__ void transpose_cvt(const float* __restrict__ in, unsigned short* __restrict__ out,
                              int R, int C) {
  __shared__ float tile[64][65];
  const int e = blockIdx.z;
  const float* inp = in + (size_t)e * R * C;
  unsigned short* outp = out + (size_t)e * R * C;
  const int c0 = blockIdx.x * 64, r0 = blockIdx.y * 64;
  const int t = threadIdx.x;
#pragma unroll
  for (int i = 0; i < 4; ++i) {
    int idx = i * 256 + t;
    int r = idx >> 4, c4 = (idx & 15) * 4;
    float4 v = *(const float4*)(inp + (size_t)(r0 + r) * C + c0 + c4);
    tile[r][c4 + 0] = v.x; tile[r][c4 + 1] = v.y;
    tile[r][c4 + 2] = v.z; tile[r][c4 + 3] = v.w;
  }
  __syncthreads();
#pragma unroll
  for (int i = 0; i < 2; ++i) {
    int idx = i * 256 + t;            // 512 items: (col, 8-row group)
    int c = idx >> 3, r8 = (idx & 7) * 8;
    unsigned short s[8];
#pragma unroll
    for (int j = 0; j < 8; ++j) s[j] = f2bf(tile[r8 + j][c]);
    uint4 o;
    o.x = (unsigned)s[0] | ((unsigned)s[1] << 16);
    o.y = (unsigned)s[2] | ((unsigned)s[3] << 16);
    o.z = (unsigned)s[4] | ((unsigned)s[5] << 16);
    o.w = (unsigned)s[6] | ((unsigned)s[7] << 16);
    *(uint4*)(outp + (size_t)(c0 + c) * R + r0 + r8) = o;
  }
}

// ---------------- 5/6. bf16 MFMA GEMM: swizzled LDS + dbuf + coalesced epilogue ---
// A [M=1024][K] bf16, B [N][K] bf16, C [M][N] bf16. 128x128 tile, BK=64.
// LDS layout swizzle: within each 64-elem row (8 chunks of 16B), physical
// chunk = logical ^ (row&7). Staging applies the swizzle on the global source
// column (global_load_lds scatter is lane-ordered, can't be changed); reads
// XOR it back. Breaks the 16-way bank conflict of the 128B row stride.
template <bool RELU, int MB, int NB>
__global__ __launch_bounds__(256)
void gemm_kernel(const unsigned short* __restrict__ A, const unsigned short* __restrict__ B,
                 const float* __restrict__ bias, unsigned short* __restrict__ C,
                 int N, int K) {
  constexpr int M = 1024;
  const int bid = blockIdx.x;
  const int e = bid / (MB * NB);
  const int r = bid - e * (MB * NB);
  const int patch = r / (MB * 4);
  const int q = r - patch * (MB * 4);
  const int mtile = q >> 2;
  const int ntile = patch * 4 + (q & 3);

  A += (size_t)e * M * K;
  B += (size_t)e * N * K;
  bias += (size_t)e * N;
  C += (size_t)e * M * N;
  const int m0 = mtile * 128;
  const int n0 = ntile * 128;
  const int tid = threadIdx.x;
  const int wave = tid >> 6, lane = tid & 63;
  const int wm = wave >> 1, wn = wave & 1;

  __shared__ __align__(16) unsigned short As[2][128 * 64];
  __shared__ __align__(16) unsigned short Bs[2][128 * 64];

  // staging: lane l covers (row = l>>3, physical chunk = l&7); it must load
  // the swizzled logical chunk (l&7)^(row&7) from global
  const int srow = lane >> 3;
  const int scol = ((lane & 7) ^ (srow & 7)) * 8;
  const unsigned short* gA = A + (size_t)(m0 + wave * 8 + srow) * K + scol;
  const unsigned short* gB = B + (size_t)(n0 + wave * 8 + srow) * K + scol;
  const int lbase = (wave * 8) * 64;

  f32x4 acc[4][4] = {};

  const int quad = lane >> 4;
  const int lxor = lane & 7;                        // == frag row & 7
  const int arowb = (wm * 64 + (lane & 15)) * 64;
  const int browb = (wn * 64 + (lane & 15)) * 64;

  // prologue: fill buffer 0
#pragma unroll
  for (int i = 0; i < 4; ++i) {
    load_lds16(gA + (size_t)i * 32 * K, &As[0][lbase + i * 32 * 64]);
    load_lds16(gB + (size_t)i * 32 * K, &Bs[0][lbase + i * 32 * 64]);
  }
  gA += 64; gB += 64;

  const int nIter = K >> 6;
  for (int it = 0; it < nIter; ++it) {
    const int cur = it & 1;
    __syncthreads();
    if (it + 1 < nIter) {
#pragma unroll
      for (int i = 0; i < 4; ++i) {
        load_lds16(gA + (size_t)i * 32 * K, &As[cur ^ 1][lbase + i * 32 * 64]);
        load_lds16(gB + (size_t)i * 32 * K, &Bs[cur ^ 1][lbase + i * 32 * 64]);
      }
      gA += 64; gB += 64;
    }
#pragma unroll
    for (int kk = 0; kk < 64; kk += 32) {
      const int coff = ((quad + (kk >> 3)) ^ lxor) * 8;  // swizzled chunk
      bf16x8 af[4], bfr[4];
#pragma unroll
      for (int i = 0; i < 4; ++i)
        af[i] = *reinterpret_cast<const bf16x8*>(&As[cur][arowb + i * 16 * 64 + coff]);
#pragma unroll
      for (int j = 0; j < 4; ++j)
        bfr[j] = *reinterpret_cast<const bf16x8*>(&Bs[cur][browb + j * 16 * 64 + coff]);
#pragma unroll
      for (int i = 0; i < 4; ++i)
#pragma unroll
        for (int j = 0; j < 4; ++j)
          acc[i][j] = __builtin_amdgcn_mfma_f32_16x16x32_bf16(af[i], bfr[j], acc[i][j], 0, 0, 0);
    }
  }

  // ---- epilogue: wave-private LDS restage -> coalesced dwordx4 stores ----
  __syncthreads();  // all waves done reading As/Bs
  // 64x64 bf16 tile per wave, row stride 72 shorts (144B: 16B-aligned, breaks banks)
  unsigned short* scr = (wave < 2 ? &As[0][0] : &Bs[0][0]) + (wave & 1) * 4608;
  const int lc = lane & 15;
#pragma unroll
  for (int j = 0; j < 4; ++j) {
    float bj = bias[n0 + wn * 64 + j * 16 + lc];
#pragma unroll
    for (int i = 0; i < 4; ++i)
#pragma unroll
      for (int rr = 0; rr < 4; ++rr) {
        float v = acc[i][j][rr] + bj;
        if (RELU) v = fmaxf(v, 0.f);
        scr[(i * 16 + quad * 4 + rr) * 72 + j * 16 + lc] = f2bf(v);
      }
  }
  __asm__ volatile("s_waitcnt lgkmcnt(0)" ::: "memory");  // wave-internal LDS RAW
  const int erow = lane >> 3;
  const int ecol = (lane & 7) * 8;
  unsigned short* Cbase = C + (size_t)(m0 + wm * 64) * N + n0 + wn * 64;
#pragma unroll
  for (int p = 0; p < 8; ++p) {
    uint4 v = *(const uint4*)&scr[(p * 8 + erow) * 72 + ecol];
    *(uint4*)&Cbase[(size_t)(p * 8 + erow) * N + ecol] = v;
  }
}

// ---------------- 7. combine: gate-weighted gather (bf16 expert out) ----------------
__global__ void combine_kernel(const unsigned short* __restrict__ outb,
                               const int* __restrict__ tok_e, const int* __restrict__ tok_loc,
                               const float* __restrict__ tok_g, float* __restrict__ y) {
  const int t = blockIdx.x;
  const int tid = threadIdx.x;  // 0..255, 4 bf16 each
  int e0 = tok_e[2 * t], e1 = tok_e[2 * t + 1];
  int l0 = tok_loc[2 * t], l1 = tok_loc[2 * t + 1];
  float g0 = tok_g[2 * t], g1 = tok_g[2 * t + 1];
  float ax = 0.f, ay = 0.f, az = 0.f, aw = 0.f;
  if (l0 >= 0) {
    uint2 u = ((const uint2*)(outb + ((size_t)e0 * CAP + l0) * DIM))[tid];
    ax += g0 * bf2f(u.x & 0xffffu); ay += g0 * __uint_as_float(u.x & 0xffff0000u);
    az += g0 * bf2f(u.y & 0xffffu); aw += g0 * __uint_as_float(u.y & 0xffff0000u);
  }
  if (l1 >= 0) {
    uint2 u = ((const uint2*)(outb + ((size_t)e1 * CAP + l1) * DIM))[tid];
    ax += g1 * bf2f(u.x & 0xffffu); ay += g1 * __uint_as_float(u.x & 0xffff0000u);
    az += g1 * bf2f(u.y & 0xffffu); aw += g1 * __uint_as_float(u.y & 0xffff0000u);
  }
  float4 o; o.x = ax; o.y = ay; o.z = az; o.w = aw;
  ((float4*)(y + (size_t)t * DIM))[tid] = o;
}

extern "C" void kernel_launch(void* const* d_in, const int* in_sizes, int n_in,
                              void* d_out, int out_size, void* d_ws, size_t ws_size,
                              hipStream_t stream) {
  const float* x  = (const float*)d_in[0];
  const float* wg = (const float*)d_in[1];
  const float* w1 = (const float*)d_in[2];
  const float* b1 = (const float*)d_in[3];
  const float* w2 = (const float*)d_in[4];
  const float* b2 = (const float*)d_in[5];
  float* y = (float*)d_out;

  char* ws = (char*)d_ws;
  int*   tok_e    = (int*)(ws);
  int*   tok_loc  = (int*)(ws + 32768);
  float* tok_g    = (float*)(ws + 65536);
  int*   slot_map = (int*)(ws + 98304);
  unsigned short* disp = (unsigned short*)(ws + 131072);                      // 16 MiB
  unsigned short* wbuf = (unsigned short*)(ws + 131072 + (16ull << 20));      // 64 MiB
  unsigned short* h    = (unsigned short*)(ws + 131072 + (80ull << 20));      // 64 MiB
  unsigned short* outb = (unsigned short*)(ws + 131072 + (144ull << 20));     // 16 MiB

  gating_kernel<<<NTOK, 64, 0, stream>>>(x, wg, tok_e, tok_g);
  scan_kernel<<<1, 64, 0, stream>>>(tok_e, tok_loc, slot_map);
  dispatch_kernel<<<NEXP * CAP, 256, 0, stream>>>(x, slot_map, disp);
  // w1 [E][D][H] -> wbuf [E][H][D] bf16
  transpose_cvt<<<dim3(HID / 64, DIM / 64, NEXP), 256, 0, stream>>>(w1, wbuf, DIM, HID);
  // h = relu(disp @ w1 + b1): M=1024, N=HID, K=DIM
  gemm_kernel<true, 8, 32><<<NEXP * 8 * 32, 256, 0, stream>>>(disp, wbuf, b1, h, HID, DIM);
  // w2 [E][H][D] -> wbuf [E][D][H] bf16
  transpose_cvt<<<dim3(DIM / 64, HID / 64, NEXP), 256, 0, stream>>>(w2, wbuf, HID, DIM);
  // out = h @ w2 + b2: M=1024, N=DIM, K=HID
  gemm_kernel<false, 8, 8><<<NEXP * 8 * 8, 256, 0, stream>>>(h, wbuf, b2, outb, DIM, HID);
  combine_kernel<<<NTOK, 256, 0, stream>>>(outb, tok_e, tok_loc, tok_g, y);
}